// Round 1
// 363.982 us; speedup vs baseline: 1.6568x; 1.6568x over previous
//
#include <hip/hip_runtime.h>
#include <math.h>

typedef __attribute__((ext_vector_type(4))) float f32x4;
typedef __attribute__((ext_vector_type(8))) short bf16x8;

#define NB   64
#define CD   128
#define TD   2048
#define QBLK 64
#define KVB  64
#define NKV  (TD / KVB)      // 32
#define VPAD (KVB + 8)       // 72 shorts = 144B rows (16B aligned)

// workspace layout: [b][mid=Q,K][tile][64 rows][128 cols] bf16 (swizzled), then V tiles
#define TILE_B   16384
#define QK_BYTES ((size_t)NB * 2 * NKV * TILE_B)   // 67,108,864
// V region: [b][tile][128 rows][64 cols] bf16 (swizzled) -> +33,554,432 (total 100.7 MB)

__device__ __forceinline__ short f2bf(float f) {
    union { float f; unsigned u; } x; x.f = f;
    unsigned r = x.u + 0x7FFFu + ((x.u >> 16) & 1u);   // RNE
    return (short)(r >> 16);
}

__device__ __forceinline__ void gl_lds16(const void* g, void* l) {
    __builtin_amdgcn_global_load_lds(
        (__attribute__((address_space(1))) void*)g,
        (__attribute__((address_space(3))) void*)l, 16, 0, 0);
}

// ---------------------------------------------------------------------------
// Prepass: fp32 -> bf16, Q/K transposed to [s][c] tiles, V natural [c][s] tiles.
// 16B-chunk XOR swizzle pre-applied in global: stored chunk p of row r holds
// data chunk p ^ (r & 7).
// ---------------------------------------------------------------------------
__global__ __launch_bounds__(256)
void prepass(const float* __restrict__ qkv, char* __restrict__ ws)
{
    int blk = blockIdx.x;
    int b   = blk / 96;
    int rem = blk - b * 96;
    int mid = rem >> 5;          // 0=Q, 1=K, 2=V
    int sb  = rem & 31;
    int s0  = sb * KVB;
    int tid = threadIdx.x;
    const float* src = qkv + ((size_t)b * 3 + mid) * CD * TD;

    if (mid < 2) {
        // transpose path: tile[row=s'][col=c], rows of 256B = 16 chunks
        __shared__ short Tl[KVB][CD + 8];    // 272B rows (16B aligned)
        int su = (tid & 15) * 4;
        int cb = 4 * (tid >> 4);
        #pragma unroll
        for (int it = 0; it < 2; ++it) {
            int c0 = cb + 64 * it;
            f32x4 r0 = *(const f32x4*)&src[(size_t)(c0 + 0) * TD + s0 + su];
            f32x4 r1 = *(const f32x4*)&src[(size_t)(c0 + 1) * TD + s0 + su];
            f32x4 r2 = *(const f32x4*)&src[(size_t)(c0 + 2) * TD + s0 + su];
            f32x4 r3 = *(const f32x4*)&src[(size_t)(c0 + 3) * TD + s0 + su];
            #pragma unroll
            for (int s = 0; s < 4; ++s) {
                short4 w;
                w.x = f2bf(r0[s]); w.y = f2bf(r1[s]);
                w.z = f2bf(r2[s]); w.w = f2bf(r3[s]);
                *(short4*)&Tl[su + s][c0] = w;
            }
        }
        __syncthreads();
        char* dst = ws + ((size_t)(b * 2 + mid) * NKV + sb) * TILE_B;
        #pragma unroll
        for (int it = 0; it < 4; ++it) {
            int row = (tid >> 4) + 16 * it;
            int p   = tid & 15;
            int q   = p ^ (row & 7);
            *(f32x4*)(dst + row * 256 + p * 16) = *(const f32x4*)&Tl[row][q * 8];
        }
    } else {
        // V path: tile[row=c][col=s'], rows of 128B = 8 chunks
        char* dst = ws + QK_BYTES + ((size_t)b * NKV + sb) * TILE_B;
        int c = tid >> 1;
        int h = tid & 1;
        #pragma unroll
        for (int i = 0; i < 4; ++i) {
            int p = 4 * h + i;
            int q = p ^ (c & 7);
            f32x4 a0 = *(const f32x4*)&src[(size_t)c * TD + s0 + q * 8];
            f32x4 a1 = *(const f32x4*)&src[(size_t)c * TD + s0 + q * 8 + 4];
            bf16x8 w;
            w[0] = f2bf(a0[0]); w[1] = f2bf(a0[1]); w[2] = f2bf(a0[2]); w[3] = f2bf(a0[3]);
            w[4] = f2bf(a1[0]); w[5] = f2bf(a1[1]); w[6] = f2bf(a1[2]); w[7] = f2bf(a1[3]);
            *(bf16x8*)(dst + c * 128 + p * 16) = w;
        }
    }
}

// ---------------------------------------------------------------------------
// Attention: bf16 tiles staged via global_load_lds (linear LDS, swizzled reads)
// ---------------------------------------------------------------------------
__global__ __launch_bounds__(256, 3)
void attn_fwd(const char* __restrict__ ws, float* __restrict__ out)
{
    // XCD-bijective decode: batch b owned by XCD b/8 (K/V stay L2-resident)
    int i    = blockIdx.x;
    int xcd  = i & 7;
    int slot = i >> 3;
    int b    = xcd * 8 + (slot >> 5);
    int tt   = slot & 31;
    int t0   = tt * QBLK;

    int tid  = threadIdx.x;
    int wid  = tid >> 6;
    int lane = tid & 63;
    int g    = lane >> 4;
    int n16  = lane & 15;

    const char* qt  = ws + ((size_t)(b * 2 + 0) * NKV + tt) * TILE_B;
    const char* ktb = ws + ((size_t)(b * 2 + 1) * NKV) * TILE_B;
    const char* vtb = ws + QK_BYTES + ((size_t)b * NKV) * TILE_B;

    __shared__ short Klds[KVB][CD];       // linear; content chunk-swizzled
    __shared__ short Vlds[CD][KVB];       // linear; content chunk-swizzled
    __shared__ short Plds[4][16][VPAD];   // per-wave P relayout
    char* kldsb = (char*)&Klds[0][0];
    char* vldsb = (char*)&Vlds[0][0];

    // ---- Q fragments direct from pre-transposed global tile ----
    bf16x8 qf[4];
    {
        int qrow = 16 * wid + n16;
        #pragma unroll
        for (int kt = 0; kt < 4; ++kt)
            qf[kt] = *(const bf16x8*)(qt + qrow * 256 + (((4 * kt + g) ^ (n16 & 7)) * 16));
    }

    const float SCALE = 0.08838834764831845f;  // 1/sqrt(128) on logits

    f32x4 o[8];
    #pragma unroll
    for (int ct = 0; ct < 8; ++ct) o[ct] = (f32x4)(0.0f);
    float mrow[4], lrow[4];
    #pragma unroll
    for (int r = 0; r < 4; ++r) { mrow[r] = -1e30f; lrow[r] = 0.0f; }

    for (int sb = 0; sb < NKV; ++sb) {
        const char* kt16 = ktb + (size_t)sb * TILE_B;
        const char* vt16 = vtb + (size_t)sb * TILE_B;
        __syncthreads();   // all waves done reading K/V of previous tile
        {
            int wb = wid * 1024;     // per-wave 64 lanes x 16B
            int lo = lane * 16;
            #pragma unroll
            for (int it = 0; it < 4; ++it)
                gl_lds16(kt16 + it * 4096 + wb + lo, kldsb + it * 4096 + wb);
            #pragma unroll
            for (int it = 0; it < 4; ++it)
                gl_lds16(vt16 + it * 4096 + wb + lo, vldsb + it * 4096 + wb);
        }
        __syncthreads();   // drains vmcnt(0): tiles resident

        // ---- QK^T: D[m=t][n=s], swizzled K chunk reads ----
        f32x4 acc[4];
        #pragma unroll
        for (int nt = 0; nt < 4; ++nt) acc[nt] = (f32x4)(0.0f);
        #pragma unroll
        for (int kt = 0; kt < 4; ++kt) {
            #pragma unroll
            for (int nt = 0; nt < 4; ++nt) {
                bf16x8 bfr = *(const bf16x8*)(kldsb + (16 * nt + n16) * 256
                                              + (((4 * kt + g) ^ (n16 & 7)) * 16));
                acc[nt] = __builtin_amdgcn_mfma_f32_16x16x32_bf16(qf[kt], bfr, acc[nt], 0, 0, 0);
            }
        }

        // ---- online softmax (fp32). Lane holds rows 4g+r, col 16nt+n16 ----
        float p[4][4];   // [nt][r]
        float pm[4];
        #pragma unroll
        for (int r = 0; r < 4; ++r) pm[r] = -1e30f;
        #pragma unroll
        for (int nt = 0; nt < 4; ++nt)
            #pragma unroll
            for (int r = 0; r < 4; ++r) {
                p[nt][r] = acc[nt][r] * SCALE;
                pm[r] = fmaxf(pm[r], p[nt][r]);
            }
        #pragma unroll
        for (int msk = 1; msk <= 8; msk <<= 1)
            #pragma unroll
            for (int r = 0; r < 4; ++r)
                pm[r] = fmaxf(pm[r], __shfl_xor(pm[r], msk, 64));
        float cr[4];
        #pragma unroll
        for (int r = 0; r < 4; ++r) {
            float mn = fmaxf(mrow[r], pm[r]);
            cr[r] = __expf(mrow[r] - mn);
            mrow[r] = mn;
        }
        float ps[4] = {0.f, 0.f, 0.f, 0.f};
        #pragma unroll
        for (int nt = 0; nt < 4; ++nt)
            #pragma unroll
            for (int r = 0; r < 4; ++r) {
                p[nt][r] = __expf(p[nt][r] - mrow[r]);
                ps[r] += p[nt][r];
            }
        #pragma unroll
        for (int msk = 1; msk <= 8; msk <<= 1)
            #pragma unroll
            for (int r = 0; r < 4; ++r)
                ps[r] += __shfl_xor(ps[r], msk, 64);
        #pragma unroll
        for (int r = 0; r < 4; ++r) lrow[r] = lrow[r] * cr[r] + ps[r];
        #pragma unroll
        for (int ct = 0; ct < 8; ++ct)
            #pragma unroll
            for (int r = 0; r < 4; ++r)
                o[ct][r] *= cr[r];

        // ---- P relayout via per-wave LDS: row 4g+r, col 16nt+n16 ----
        #pragma unroll
        for (int nt = 0; nt < 4; ++nt)
            #pragma unroll
            for (int r = 0; r < 4; ++r)
                Plds[wid][4 * g + r][16 * nt + n16] = f2bf(p[nt][r]);

        // ---- PV: A = P[m=t'][k=s], B = V[k=s][n=c], swizzled V chunk reads ----
        #pragma unroll
        for (int kt2 = 0; kt2 < 2; ++kt2) {
            bf16x8 pa = *(const bf16x8*)&Plds[wid][n16][32 * kt2 + 8 * g];
            #pragma unroll
            for (int ct = 0; ct < 8; ++ct) {
                bf16x8 vf = *(const bf16x8*)(vldsb + (16 * ct + n16) * 128
                                             + (((4 * kt2 + g) ^ (n16 & 7)) * 16));
                o[ct] = __builtin_amdgcn_mfma_f32_16x16x32_bf16(pa, vf, o[ct], 0, 0, 0);
            }
        }
    }

    // ---- epilogue: normalize and store out[b][c][t] ----
    float inv[4];
    #pragma unroll
    for (int r = 0; r < 4; ++r) inv[r] = 1.0f / lrow[r];
    float* ob = out + (size_t)b * CD * TD;
    int tbase = t0 + 16 * wid + 4 * g;
    #pragma unroll
    for (int ct = 0; ct < 8; ++ct) {
        int c = 16 * ct + n16;
        #pragma unroll
        for (int r = 0; r < 4; ++r)
            ob[(size_t)c * TD + tbase + r] = o[ct][r] * inv[r];
    }
}

extern "C" void kernel_launch(void* const* d_in, const int* in_sizes, int n_in,
                              void* d_out, int out_size, void* d_ws, size_t ws_size,
                              hipStream_t stream)
{
    const float* qkv = (const float*)d_in[0];
    float* out = (float*)d_out;
    char* ws = (char*)d_ws;
    prepass<<<dim3(NB * 96), 256, 0, stream>>>(qkv, ws);                 // 6144 wgs
    attn_fwd<<<dim3(NB * (TD / QBLK)), 256, 0, stream>>>(ws, out);       // 2048 wgs
}

// Round 2
// 351.827 us; speedup vs baseline: 1.7140x; 1.0345x over previous
//
#include <hip/hip_runtime.h>
#include <math.h>

typedef __attribute__((ext_vector_type(4))) float f32x4;
typedef __attribute__((ext_vector_type(8))) short bf16x8;

#define NB   64
#define CD   128
#define TD   2048
#define QBLK 64
#define KVB  64
#define NKV  (TD / KVB)      // 32
#define VPAD (KVB + 8)       // 72 shorts = 144B rows (16B aligned)

// workspace layout: [b][mid=Q,K][tile][64 rows][128 cols] bf16 (swizzled), then V tiles
#define TILE_B   16384
#define QK_BYTES ((size_t)NB * 2 * NKV * TILE_B)   // 67,108,864
// V region: [b][tile][128 rows][64 cols] bf16 (swizzled) -> +33,554,432 (total 100.7 MB)

__device__ __forceinline__ short f2bf(float f) {
    union { float f; unsigned u; } x; x.f = f;
    unsigned r = x.u + 0x7FFFu + ((x.u >> 16) & 1u);   // RNE
    return (short)(r >> 16);
}

__device__ __forceinline__ void gl_lds16(const void* g, void* l) {
    __builtin_amdgcn_global_load_lds(
        (__attribute__((address_space(1))) void*)g,
        (__attribute__((address_space(3))) void*)l, 16, 0, 0);
}

// ---------------------------------------------------------------------------
// Prepass: fp32 -> bf16, Q/K transposed to [s][c] tiles, V natural [c][s] tiles.
// 16B-chunk XOR swizzle pre-applied in global: stored chunk p of row r holds
// data chunk p ^ (r & 7).
// ---------------------------------------------------------------------------
__global__ __launch_bounds__(256)
void prepass(const float* __restrict__ qkv, char* __restrict__ ws)
{
    int blk = blockIdx.x;
    int b   = blk / 96;
    int rem = blk - b * 96;
    int mid = rem >> 5;          // 0=Q, 1=K, 2=V
    int sb  = rem & 31;
    int s0  = sb * KVB;
    int tid = threadIdx.x;
    const float* src = qkv + ((size_t)b * 3 + mid) * CD * TD;

    if (mid < 2) {
        // transpose path: tile[row=s'][col=c], rows of 256B = 16 chunks
        __shared__ short Tl[KVB][CD + 8];    // 272B rows (16B aligned)
        int su = (tid & 15) * 4;
        int cb = 4 * (tid >> 4);
        #pragma unroll
        for (int it = 0; it < 2; ++it) {
            int c0 = cb + 64 * it;
            f32x4 r0 = *(const f32x4*)&src[(size_t)(c0 + 0) * TD + s0 + su];
            f32x4 r1 = *(const f32x4*)&src[(size_t)(c0 + 1) * TD + s0 + su];
            f32x4 r2 = *(const f32x4*)&src[(size_t)(c0 + 2) * TD + s0 + su];
            f32x4 r3 = *(const f32x4*)&src[(size_t)(c0 + 3) * TD + s0 + su];
            #pragma unroll
            for (int s = 0; s < 4; ++s) {
                short4 w;
                w.x = f2bf(r0[s]); w.y = f2bf(r1[s]);
                w.z = f2bf(r2[s]); w.w = f2bf(r3[s]);
                *(short4*)&Tl[su + s][c0] = w;
            }
        }
        __syncthreads();
        char* dst = ws + ((size_t)(b * 2 + mid) * NKV + sb) * TILE_B;
        #pragma unroll
        for (int it = 0; it < 4; ++it) {
            int row = (tid >> 4) + 16 * it;
            int p   = tid & 15;
            int q   = p ^ (row & 7);
            *(f32x4*)(dst + row * 256 + p * 16) = *(const f32x4*)&Tl[row][q * 8];
        }
    } else {
        // V path: tile[row=c][col=s'], rows of 128B = 8 chunks
        char* dst = ws + QK_BYTES + ((size_t)b * NKV + sb) * TILE_B;
        int c = tid >> 1;
        int h = tid & 1;
        #pragma unroll
        for (int i = 0; i < 4; ++i) {
            int p = 4 * h + i;
            int q = p ^ (c & 7);
            f32x4 a0 = *(const f32x4*)&src[(size_t)c * TD + s0 + q * 8];
            f32x4 a1 = *(const f32x4*)&src[(size_t)c * TD + s0 + q * 8 + 4];
            bf16x8 w;
            w[0] = f2bf(a0[0]); w[1] = f2bf(a0[1]); w[2] = f2bf(a0[2]); w[3] = f2bf(a0[3]);
            w[4] = f2bf(a1[0]); w[5] = f2bf(a1[1]); w[6] = f2bf(a1[2]); w[7] = f2bf(a1[3]);
            *(bf16x8*)(dst + c * 128 + p * 16) = w;
        }
    }
}

// ---------------------------------------------------------------------------
// Attention: counted-vmcnt pipeline, raw barriers, setprio, defer-max
// ---------------------------------------------------------------------------
__global__ __launch_bounds__(256, 3)
void attn_fwd(const char* __restrict__ ws, float* __restrict__ out)
{
    // XCD-bijective decode: batch b owned by XCD b/8 (K/V stay L2-resident)
    int i    = blockIdx.x;
    int xcd  = i & 7;
    int slot = i >> 3;
    int b    = xcd * 8 + (slot >> 5);
    int tt   = slot & 31;
    int t0   = tt * QBLK;

    int tid  = threadIdx.x;
    int wid  = tid >> 6;
    int lane = tid & 63;
    int g    = lane >> 4;
    int n16  = lane & 15;

    const char* qt  = ws + ((size_t)(b * 2 + 0) * NKV + tt) * TILE_B;
    const char* ktb = ws + ((size_t)(b * 2 + 1) * NKV) * TILE_B;
    const char* vtb = ws + QK_BYTES + ((size_t)b * NKV) * TILE_B;

    __shared__ short Klds[KVB][CD];       // linear; content chunk-swizzled
    __shared__ short Vlds[CD][KVB];       // linear; content chunk-swizzled
    __shared__ short Plds[4][16][VPAD];   // per-wave P relayout
    char* kldsb = (char*)&Klds[0][0];
    char* vldsb = (char*)&Vlds[0][0];

    int wb = wid * 1024;     // per-wave 64 lanes x 16B
    int lo = lane * 16;

    // ---- Q fragments direct from pre-transposed global tile ----
    bf16x8 qf[4];
    {
        int qrow = 16 * wid + n16;
        #pragma unroll
        for (int kt = 0; kt < 4; ++kt)
            qf[kt] = *(const bf16x8*)(qt + qrow * 256 + (((4 * kt + g) ^ (n16 & 7)) * 16));
    }

    // ---- prologue: stage K[0] then V[0] (order matters for counted vmcnt) ----
    #pragma unroll
    for (int it = 0; it < 4; ++it)
        gl_lds16(ktb + it * 4096 + wb + lo, kldsb + it * 4096 + wb);
    #pragma unroll
    for (int it = 0; it < 4; ++it)
        gl_lds16(vtb + it * 4096 + wb + lo, vldsb + it * 4096 + wb);

    const float SCALE = 0.08838834764831845f;  // 1/sqrt(128) on logits

    f32x4 o[8];
    #pragma unroll
    for (int ct = 0; ct < 8; ++ct) o[ct] = (f32x4)(0.0f);
    float mrow[4], lrow[4];
    #pragma unroll
    for (int r = 0; r < 4; ++r) { mrow[r] = -1e30f; lrow[r] = 0.0f; }

    for (int sb = 0; sb < NKV; ++sb) {
        int nxt = sb + 1;
        int notlast = (nxt < NKV);

        // ---- K[sb] resident (V[sb] still in flight) ----
        asm volatile("s_waitcnt vmcnt(4)" ::: "memory");
        __builtin_amdgcn_sched_barrier(0);
        __builtin_amdgcn_s_barrier();

        // ---- QK^T: D[m=t][n=s], swizzled K chunk reads ----
        f32x4 acc[4];
        #pragma unroll
        for (int nt = 0; nt < 4; ++nt) acc[nt] = (f32x4)(0.0f);
        __builtin_amdgcn_s_setprio(1);
        #pragma unroll
        for (int kt = 0; kt < 4; ++kt) {
            #pragma unroll
            for (int nt = 0; nt < 4; ++nt) {
                bf16x8 bfr = *(const bf16x8*)(kldsb + (16 * nt + n16) * 256
                                              + (((4 * kt + g) ^ (n16 & 7)) * 16));
                acc[nt] = __builtin_amdgcn_mfma_f32_16x16x32_bf16(qf[kt], bfr, acc[nt], 0, 0, 0);
            }
        }
        __builtin_amdgcn_s_setprio(0);

        // ---- Klds free -> prefetch K[sb+1] (flies under softmax+PV) ----
        asm volatile("s_waitcnt lgkmcnt(0)" ::: "memory");
        __builtin_amdgcn_sched_barrier(0);
        __builtin_amdgcn_s_barrier();
        if (notlast) {
            const char* kn = ktb + (size_t)nxt * TILE_B;
            #pragma unroll
            for (int it = 0; it < 4; ++it)
                gl_lds16(kn + it * 4096 + wb + lo, kldsb + it * 4096 + wb);
        }

        // ---- online softmax (fp32). Lane holds rows 4g+r, col 16nt+n16 ----
        float p[4][4];   // [nt][r]
        float pm[4];
        #pragma unroll
        for (int r = 0; r < 4; ++r) pm[r] = -1e30f;
        #pragma unroll
        for (int nt = 0; nt < 4; ++nt)
            #pragma unroll
            for (int r = 0; r < 4; ++r) {
                p[nt][r] = acc[nt][r] * SCALE;
                pm[r] = fmaxf(pm[r], p[nt][r]);
            }
        #pragma unroll
        for (int msk = 1; msk <= 8; msk <<= 1)
            #pragma unroll
            for (int r = 0; r < 4; ++r)
                pm[r] = fmaxf(pm[r], __shfl_xor(pm[r], msk, 64));

        // T13 defer-max: only rescale when tile max grew past threshold
        int ok = 1;
        #pragma unroll
        for (int r = 0; r < 4; ++r) ok &= (pm[r] <= mrow[r] + 8.0f) ? 1 : 0;
        if (!__all(ok)) {
            float cr[4];
            #pragma unroll
            for (int r = 0; r < 4; ++r) {
                float mn = fmaxf(mrow[r], pm[r]);
                cr[r] = __expf(mrow[r] - mn);
                mrow[r] = mn;
                lrow[r] *= cr[r];
            }
            #pragma unroll
            for (int ct = 0; ct < 8; ++ct)
                #pragma unroll
                for (int r = 0; r < 4; ++r)
                    o[ct][r] *= cr[r];
        }
        float ps[4] = {0.f, 0.f, 0.f, 0.f};
        #pragma unroll
        for (int nt = 0; nt < 4; ++nt)
            #pragma unroll
            for (int r = 0; r < 4; ++r) {
                p[nt][r] = __expf(p[nt][r] - mrow[r]);   // bounded by e^8 when deferred
                ps[r] += p[nt][r];
            }
        #pragma unroll
        for (int msk = 1; msk <= 8; msk <<= 1)
            #pragma unroll
            for (int r = 0; r < 4; ++r)
                ps[r] += __shfl_xor(ps[r], msk, 64);
        #pragma unroll
        for (int r = 0; r < 4; ++r) lrow[r] += ps[r];

        // ---- P relayout via per-wave LDS (no cross-wave sync needed) ----
        #pragma unroll
        for (int nt = 0; nt < 4; ++nt)
            #pragma unroll
            for (int r = 0; r < 4; ++r)
                Plds[wid][4 * g + r][16 * nt + n16] = f2bf(p[nt][r]);

        // ---- V[sb] resident (K[sb+1] still in flight) ----
        if (notlast) { asm volatile("s_waitcnt vmcnt(4)" ::: "memory"); }
        else         { asm volatile("s_waitcnt vmcnt(0)" ::: "memory"); }
        __builtin_amdgcn_sched_barrier(0);
        __builtin_amdgcn_s_barrier();

        // ---- PV: A = P[m=t'][k=s], B = V[k=s][n=c], swizzled V chunk reads ----
        __builtin_amdgcn_s_setprio(1);
        #pragma unroll
        for (int kt2 = 0; kt2 < 2; ++kt2) {
            bf16x8 pa = *(const bf16x8*)&Plds[wid][n16][32 * kt2 + 8 * g];
            #pragma unroll
            for (int ct = 0; ct < 8; ++ct) {
                bf16x8 vf = *(const bf16x8*)(vldsb + (16 * ct + n16) * 128
                                             + (((4 * kt2 + g) ^ (n16 & 7)) * 16));
                o[ct] = __builtin_amdgcn_mfma_f32_16x16x32_bf16(pa, vf, o[ct], 0, 0, 0);
            }
        }
        __builtin_amdgcn_s_setprio(0);

        // ---- Vlds free -> prefetch V[sb+1] (flies under next QK^T+softmax) ----
        asm volatile("s_waitcnt lgkmcnt(0)" ::: "memory");
        __builtin_amdgcn_sched_barrier(0);
        __builtin_amdgcn_s_barrier();
        if (notlast) {
            const char* vn = vtb + (size_t)nxt * TILE_B;
            #pragma unroll
            for (int it = 0; it < 4; ++it)
                gl_lds16(vn + it * 4096 + wb + lo, vldsb + it * 4096 + wb);
        }
    }

    // ---- epilogue: normalize and store out[b][c][t] ----
    float inv[4];
    #pragma unroll
    for (int r = 0; r < 4; ++r) inv[r] = 1.0f / lrow[r];
    float* ob = out + (size_t)b * CD * TD;
    int tbase = t0 + 16 * wid + 4 * g;
    #pragma unroll
    for (int ct = 0; ct < 8; ++ct) {
        int c = 16 * ct + n16;
        #pragma unroll
        for (int r = 0; r < 4; ++r)
            ob[(size_t)c * TD + tbase + r] = o[ct][r] * inv[r];
    }
}

extern "C" void kernel_launch(void* const* d_in, const int* in_sizes, int n_in,
                              void* d_out, int out_size, void* d_ws, size_t ws_size,
                              hipStream_t stream)
{
    const float* qkv = (const float*)d_in[0];
    float* out = (float*)d_out;
    char* ws = (char*)d_ws;
    prepass<<<dim3(NB * 96), 256, 0, stream>>>(qkv, ws);                 // 6144 wgs
    attn_fwd<<<dim3(NB * (TD / QBLK)), 256, 0, stream>>>(ws, out);       // 2048 wgs
}

// Round 3
// 256.972 us; speedup vs baseline: 2.3467x; 1.3691x over previous
//
#include <hip/hip_runtime.h>
#include <math.h>

typedef __attribute__((ext_vector_type(4))) float f32x4;
typedef __attribute__((ext_vector_type(8))) short bf16x8;

#define NB   64
#define CD   128
#define TD   2048
#define QBLK 64
#define KVB  64
#define NKV  (TD / KVB)      // 32

// workspace layout: [b][mid=Q,K][tile][64 rows][128 cols] bf16 (swizzled), then V tiles
#define TILE_B   16384
#define QK_BYTES ((size_t)NB * 2 * NKV * TILE_B)   // 67,108,864
// V region: [b][tile][128 rows][64 cols] bf16 (swizzled) -> +33,554,432 (total 100.7 MB)

__device__ __forceinline__ short f2bf(float f) {
    union { float f; unsigned u; } x; x.f = f;
    unsigned r = x.u + 0x7FFFu + ((x.u >> 16) & 1u);   // RNE
    return (short)(r >> 16);
}

__device__ __forceinline__ void gl_lds16(const void* g, void* l) {
    __builtin_amdgcn_global_load_lds(
        (__attribute__((address_space(1))) void*)g,
        (__attribute__((address_space(3))) void*)l, 16, 0, 0);
}

// ---------------------------------------------------------------------------
// Prepass: fp32 -> bf16, Q/K transposed to [s][c] tiles, V natural [c][s] tiles.
// 16B-chunk XOR swizzle pre-applied in global: stored chunk p of row r holds
// data chunk p ^ (r & 7).
// ---------------------------------------------------------------------------
__global__ __launch_bounds__(256)
void prepass(const float* __restrict__ qkv, char* __restrict__ ws)
{
    int blk = blockIdx.x;
    int b   = blk / 96;
    int rem = blk - b * 96;
    int mid = rem >> 5;          // 0=Q, 1=K, 2=V
    int sb  = rem & 31;
    int s0  = sb * KVB;
    int tid = threadIdx.x;
    const float* src = qkv + ((size_t)b * 3 + mid) * CD * TD;

    if (mid < 2) {
        // transpose path: tile[row=s'][col=c], rows of 256B = 16 chunks
        __shared__ short Tl[KVB][CD + 8];    // 272B rows (16B aligned)
        int su = (tid & 15) * 4;
        int cb = 4 * (tid >> 4);
        #pragma unroll
        for (int it = 0; it < 2; ++it) {
            int c0 = cb + 64 * it;
            f32x4 r0 = *(const f32x4*)&src[(size_t)(c0 + 0) * TD + s0 + su];
            f32x4 r1 = *(const f32x4*)&src[(size_t)(c0 + 1) * TD + s0 + su];
            f32x4 r2 = *(const f32x4*)&src[(size_t)(c0 + 2) * TD + s0 + su];
            f32x4 r3 = *(const f32x4*)&src[(size_t)(c0 + 3) * TD + s0 + su];
            #pragma unroll
            for (int s = 0; s < 4; ++s) {
                short4 w;
                w.x = f2bf(r0[s]); w.y = f2bf(r1[s]);
                w.z = f2bf(r2[s]); w.w = f2bf(r3[s]);
                *(short4*)&Tl[su + s][c0] = w;
            }
        }
        __syncthreads();
        char* dst = ws + ((size_t)(b * 2 + mid) * NKV + sb) * TILE_B;
        #pragma unroll
        for (int it = 0; it < 4; ++it) {
            int row = (tid >> 4) + 16 * it;
            int p   = tid & 15;
            int q   = p ^ (row & 7);
            *(f32x4*)(dst + row * 256 + p * 16) = *(const f32x4*)&Tl[row][q * 8];
        }
    } else {
        // V path: tile[row=c][col=s'], rows of 128B = 8 chunks
        char* dst = ws + QK_BYTES + ((size_t)b * NKV + sb) * TILE_B;
        int c = tid >> 1;
        int h = tid & 1;
        #pragma unroll
        for (int i = 0; i < 4; ++i) {
            int p = 4 * h + i;
            int q = p ^ (c & 7);
            f32x4 a0 = *(const f32x4*)&src[(size_t)c * TD + s0 + q * 8];
            f32x4 a1 = *(const f32x4*)&src[(size_t)c * TD + s0 + q * 8 + 4];
            bf16x8 w;
            w[0] = f2bf(a0[0]); w[1] = f2bf(a0[1]); w[2] = f2bf(a0[2]); w[3] = f2bf(a0[3]);
            w[4] = f2bf(a1[0]); w[5] = f2bf(a1[1]); w[6] = f2bf(a1[2]); w[7] = f2bf(a1[3]);
            *(bf16x8*)(dst + c * 128 + p * 16) = w;
        }
    }
}

// ---------------------------------------------------------------------------
// Attention: 4 blocks/CU, shuffle-free steady-state softmax, uniform pipeline
// ---------------------------------------------------------------------------
__global__ __launch_bounds__(256, 4)
void attn_fwd(const char* __restrict__ ws, float* __restrict__ out)
{
    // XCD-bijective decode: batch b owned by XCD b/8 (K/V stay L2-resident)
    int i    = blockIdx.x;
    int xcd  = i & 7;
    int slot = i >> 3;
    int b    = xcd * 8 + (slot >> 5);
    int tt   = slot & 31;
    int t0   = tt * QBLK;

    int tid  = threadIdx.x;
    int wid  = tid >> 6;
    int lane = tid & 63;
    int g    = lane >> 4;
    int n16  = lane & 15;

    const char* qt  = ws + ((size_t)(b * 2 + 0) * NKV + tt) * TILE_B;
    const char* ktb = ws + ((size_t)(b * 2 + 1) * NKV) * TILE_B;
    const char* vtb = ws + QK_BYTES + ((size_t)b * NKV) * TILE_B;

    __shared__ short Klds[KVB][CD];       // linear; content chunk-swizzled (16KB)
    __shared__ short Vlds[CD][KVB];       // linear; content chunk-swizzled (16KB)
    __shared__ short Plds[4][1024];       // per-wave P, (nt,r,g,n16) layout (8KB)
    char* kldsb = (char*)&Klds[0][0];
    char* vldsb = (char*)&Vlds[0][0];
    short* pw   = &Plds[wid][0];

    int wb = wid * 1024;     // per-wave 64 lanes x 16B
    int lo = lane * 16;

    // ---- Q fragments direct from pre-transposed global tile ----
    bf16x8 qf[4];
    {
        int qrow = 16 * wid + n16;
        #pragma unroll
        for (int kt = 0; kt < 4; ++kt)
            qf[kt] = *(const bf16x8*)(qt + qrow * 256 + (((4 * kt + g) ^ (n16 & 7)) * 16));
    }

    // per-lane invariant offsets for P (bytes): conflict-free permuted layout
    // store P[4g+r][16nt+n16] at nt*512 + r*128 + g*32 + n16*2
    int pwr = g * 32 + n16 * 2;
    // read  P[n16][32kt2+8g+j] at (2kt2+(g>>1))*512 + (n16&3)*128 + (n16>>2)*32 + (g&1)*16
    int par = (g >> 1) ? 512 : 0;
    par += (n16 & 3) * 128 + (n16 >> 2) * 32 + (g & 1) * 16;

    // ---- prologue: stage K[0] then V[0] (order matters for counted vmcnt) ----
    #pragma unroll
    for (int it = 0; it < 4; ++it)
        gl_lds16(ktb + it * 4096 + wb + lo, kldsb + it * 4096 + wb);
    #pragma unroll
    for (int it = 0; it < 4; ++it)
        gl_lds16(vtb + it * 4096 + wb + lo, vldsb + it * 4096 + wb);

    const float SCALE = 0.08838834764831845f;  // 1/sqrt(128) on logits

    f32x4 o[8];
    #pragma unroll
    for (int ct = 0; ct < 8; ++ct) o[ct] = (f32x4)(0.0f);
    float mrow[4], lsum[4];
    #pragma unroll
    for (int r = 0; r < 4; ++r) { mrow[r] = -1e30f; lsum[r] = 0.0f; }

    for (int sb = 0; sb < NKV; ++sb) {
        int nxt = (sb + 1 < NKV) ? (sb + 1) : sb;   // clamped: uniform pipeline

        // ---- K[sb] resident (V[sb] still in flight) ----
        asm volatile("s_waitcnt vmcnt(4)" ::: "memory");
        __builtin_amdgcn_sched_barrier(0);
        __builtin_amdgcn_s_barrier();

        // ---- QK^T: D[m=t][n=s], swizzled K chunk reads ----
        f32x4 acc[4];
        #pragma unroll
        for (int nt = 0; nt < 4; ++nt) acc[nt] = (f32x4)(0.0f);
        __builtin_amdgcn_s_setprio(1);
        #pragma unroll
        for (int kt = 0; kt < 4; ++kt) {
            #pragma unroll
            for (int nt = 0; nt < 4; ++nt) {
                bf16x8 bfr = *(const bf16x8*)(kldsb + (16 * nt + n16) * 256
                                              + (((4 * kt + g) ^ (n16 & 7)) * 16));
                acc[nt] = __builtin_amdgcn_mfma_f32_16x16x32_bf16(qf[kt], bfr, acc[nt], 0, 0, 0);
            }
        }
        __builtin_amdgcn_s_setprio(0);

        // ---- Klds free -> prefetch K[nxt] (flies under softmax+PV) ----
        asm volatile("s_waitcnt lgkmcnt(0)" ::: "memory");
        __builtin_amdgcn_sched_barrier(0);
        __builtin_amdgcn_s_barrier();
        {
            const char* kn = ktb + (size_t)nxt * TILE_B;
            #pragma unroll
            for (int it = 0; it < 4; ++it)
                gl_lds16(kn + it * 4096 + wb + lo, kldsb + it * 4096 + wb);
        }

        // ---- softmax, shuffle-free fast path. Lane: rows 4g+r, col 16nt+n16 ----
        float p[4][4];   // [nt][r]
        float pm[4];     // per-lane partial max (over nt only)
        #pragma unroll
        for (int r = 0; r < 4; ++r) pm[r] = -1e30f;
        #pragma unroll
        for (int nt = 0; nt < 4; ++nt)
            #pragma unroll
            for (int r = 0; r < 4; ++r) {
                p[nt][r] = acc[nt][r] * SCALE;
                pm[r] = fmaxf(pm[r], p[nt][r]);
            }

        // defer-max: partial-max check is equivalent to full-row check under __all
        int ok = 1;
        #pragma unroll
        for (int r = 0; r < 4; ++r) ok &= (pm[r] <= mrow[r] + 8.0f) ? 1 : 0;
        if (!__all(ok)) {
            // rare: full row-max reduce, rescale running state
            #pragma unroll
            for (int msk = 1; msk <= 8; msk <<= 1)
                #pragma unroll
                for (int r = 0; r < 4; ++r)
                    pm[r] = fmaxf(pm[r], __shfl_xor(pm[r], msk, 64));
            float cr[4];
            #pragma unroll
            for (int r = 0; r < 4; ++r) {
                float mn = fmaxf(mrow[r], pm[r]);
                cr[r] = __expf(mrow[r] - mn);
                mrow[r] = mn;
                lsum[r] *= cr[r];
            }
            #pragma unroll
            for (int ct = 0; ct < 8; ++ct)
                #pragma unroll
                for (int r = 0; r < 4; ++r)
                    o[ct][r] *= cr[r];
        }
        #pragma unroll
        for (int nt = 0; nt < 4; ++nt)
            #pragma unroll
            for (int r = 0; r < 4; ++r) {
                p[nt][r] = __expf(p[nt][r] - mrow[r]);   // bounded by e^8 when deferred
                lsum[r] += p[nt][r];                     // per-lane partial denominator
            }

        // ---- P relayout (per-wave LDS, conflict-free permuted layout) ----
        #pragma unroll
        for (int nt = 0; nt < 4; ++nt)
            #pragma unroll
            for (int r = 0; r < 4; ++r)
                *(short*)((char*)pw + nt * 512 + r * 128 + pwr) = f2bf(p[nt][r]);

        // ---- V[sb] resident (K[nxt] still in flight) ----
        asm volatile("s_waitcnt vmcnt(4)" ::: "memory");
        __builtin_amdgcn_sched_barrier(0);
        __builtin_amdgcn_s_barrier();

        // ---- PV: A = P[m=t'][k=s], B = V[k=s][n=c], swizzled V chunk reads ----
        __builtin_amdgcn_s_setprio(1);
        #pragma unroll
        for (int kt2 = 0; kt2 < 2; ++kt2) {
            bf16x8 pa = *(const bf16x8*)((char*)pw + kt2 * 1024 + par);
            #pragma unroll
            for (int ct = 0; ct < 8; ++ct) {
                bf16x8 vf = *(const bf16x8*)(vldsb + (16 * ct + n16) * 128
                                             + (((4 * kt2 + g) ^ (n16 & 7)) * 16));
                o[ct] = __builtin_amdgcn_mfma_f32_16x16x32_bf16(pa, vf, o[ct], 0, 0, 0);
            }
        }
        __builtin_amdgcn_s_setprio(0);

        // ---- Vlds free -> prefetch V[nxt] (flies under next QK^T+softmax) ----
        asm volatile("s_waitcnt lgkmcnt(0)" ::: "memory");
        __builtin_amdgcn_sched_barrier(0);
        __builtin_amdgcn_s_barrier();
        {
            const char* vn = vtb + (size_t)nxt * TILE_B;
            #pragma unroll
            for (int it = 0; it < 4; ++it)
                gl_lds16(vn + it * 4096 + wb + lo, vldsb + it * 4096 + wb);
        }
    }

    // drain redundant tail prefetch before exit
    asm volatile("s_waitcnt vmcnt(0)" ::: "memory");
    __builtin_amdgcn_sched_barrier(0);

    // ---- epilogue: one-time denominator reduce, vectorized stores ----
    #pragma unroll
    for (int msk = 1; msk <= 8; msk <<= 1)
        #pragma unroll
        for (int r = 0; r < 4; ++r)
            lsum[r] += __shfl_xor(lsum[r], msk, 64);
    float inv[4];
    #pragma unroll
    for (int r = 0; r < 4; ++r) inv[r] = 1.0f / lsum[r];

    float* ob = out + (size_t)b * CD * TD;
    int tbase = t0 + 16 * wid + 4 * g;
    #pragma unroll
    for (int ct = 0; ct < 8; ++ct) {
        int c = 16 * ct + n16;
        f32x4 w;
        #pragma unroll
        for (int r = 0; r < 4; ++r) w[r] = o[ct][r] * inv[r];
        *(f32x4*)&ob[(size_t)c * TD + tbase] = w;
    }
}

extern "C" void kernel_launch(void* const* d_in, const int* in_sizes, int n_in,
                              void* d_out, int out_size, void* d_ws, size_t ws_size,
                              hipStream_t stream)
{
    const float* qkv = (const float*)d_in[0];
    float* out = (float*)d_out;
    char* ws = (char*)d_ws;
    prepass<<<dim3(NB * 96), 256, 0, stream>>>(qkv, ws);                 // 6144 wgs
    attn_fwd<<<dim3(NB * (TD / QBLK)), 256, 0, stream>>>(ws, out);       // 2048 wgs
}

// Round 4
// 237.247 us; speedup vs baseline: 2.5418x; 1.0831x over previous
//
#include <hip/hip_runtime.h>
#include <math.h>

typedef __attribute__((ext_vector_type(4)))  float f32x4;
typedef __attribute__((ext_vector_type(16))) float f32x16;
typedef __attribute__((ext_vector_type(8)))  short bf16x8;

#define NB   64
#define CD   128
#define TD   2048
#define QBLK 128             // per block (4 waves x 32 rows)
#define KVB  64
#define NKV  (TD / KVB)      // 32
#define NQT  (TD / QBLK)     // 16

#define TILE_B   16384       // K tile: 64x128 bf16 ; V tile: 128x64 bf16
#define VBASE    ((size_t)NB * NKV * TILE_B)   // 33,554,432 (total ws = 64 MB)

__device__ __forceinline__ short f2bf(float f) {
    union { float f; unsigned u; } x; x.f = f;
    unsigned r = x.u + 0x7FFFu + ((x.u >> 16) & 1u);   // RNE
    return (short)(r >> 16);
}

__device__ __forceinline__ void gl_lds16(const void* g, void* l) {
    __builtin_amdgcn_global_load_lds(
        (__attribute__((address_space(1))) void*)g,
        (__attribute__((address_space(3))) void*)l, 16, 0, 0);
}

// ---------------------------------------------------------------------------
// Prepass: K -> [s][c] transposed bf16 tiles; V -> [c][s] natural bf16 tiles.
// 16B-chunk XOR swizzle pre-applied in global: stored chunk p of row r holds
// data chunk p ^ (r & 7).  (Q is consumed fp32 directly by attn.)
// ---------------------------------------------------------------------------
__global__ __launch_bounds__(256)
void prepass(const float* __restrict__ qkv, char* __restrict__ ws)
{
    int blk  = blockIdx.x;            // 64 b * 64 tiles
    int b    = blk >> 6;
    int rem  = blk & 63;
    int kind = rem >> 5;              // 0=K, 1=V
    int sb   = rem & 31;
    int s0   = sb * KVB;
    int tid  = threadIdx.x;
    const float* src = qkv + ((size_t)b * 3 + 1 + kind) * CD * TD;

    if (kind == 0) {
        // K transpose: tile[row=s'][col=c], rows of 256B = 16 chunks
        __shared__ short Tl[KVB][CD + 8];
        int su = (tid & 15) * 4;
        int cb = 4 * (tid >> 4);
        #pragma unroll
        for (int it = 0; it < 2; ++it) {
            int c0 = cb + 64 * it;
            f32x4 r0 = *(const f32x4*)&src[(size_t)(c0 + 0) * TD + s0 + su];
            f32x4 r1 = *(const f32x4*)&src[(size_t)(c0 + 1) * TD + s0 + su];
            f32x4 r2 = *(const f32x4*)&src[(size_t)(c0 + 2) * TD + s0 + su];
            f32x4 r3 = *(const f32x4*)&src[(size_t)(c0 + 3) * TD + s0 + su];
            #pragma unroll
            for (int s = 0; s < 4; ++s) {
                short4 w;
                w.x = f2bf(r0[s]); w.y = f2bf(r1[s]);
                w.z = f2bf(r2[s]); w.w = f2bf(r3[s]);
                *(short4*)&Tl[su + s][c0] = w;
            }
        }
        __syncthreads();
        char* dst = ws + ((size_t)b * NKV + sb) * TILE_B;
        #pragma unroll
        for (int it = 0; it < 4; ++it) {
            int row = (tid >> 4) + 16 * it;
            int p   = tid & 15;
            int q   = p ^ (row & 7);
            *(f32x4*)(dst + row * 256 + p * 16) = *(const f32x4*)&Tl[row][q * 8];
        }
    } else {
        // V natural: tile[row=c][col=s'], rows of 128B = 8 chunks
        char* dst = ws + VBASE + ((size_t)b * NKV + sb) * TILE_B;
        int c = tid >> 1;
        int hh = tid & 1;
        #pragma unroll
        for (int i = 0; i < 4; ++i) {
            int p = 4 * hh + i;
            int q = p ^ (c & 7);
            f32x4 a0 = *(const f32x4*)&src[(size_t)c * TD + s0 + q * 8];
            f32x4 a1 = *(const f32x4*)&src[(size_t)c * TD + s0 + q * 8 + 4];
            bf16x8 w;
            w[0] = f2bf(a0[0]); w[1] = f2bf(a0[1]); w[2] = f2bf(a0[2]); w[3] = f2bf(a0[3]);
            w[4] = f2bf(a1[0]); w[5] = f2bf(a1[1]); w[6] = f2bf(a1[2]); w[7] = f2bf(a1[3]);
            *(bf16x8*)(dst + c * 128 + p * 16) = w;
        }
    }
}

// ---------------------------------------------------------------------------
// Attention: 32-row waves (32x32x16 MFMA), swapped QK^T and PV, in-register P,
// per-lane scalar softmax state (exp2 domain), counted-vmcnt pipeline.
// ---------------------------------------------------------------------------
__global__ __launch_bounds__(256, 3)
void attn_fwd(const float* __restrict__ qkv, const char* __restrict__ ws,
              float* __restrict__ out)
{
    // XCD-bijective decode: batch b owned by XCD b/8 (K/V stay L2-resident)
    int i    = blockIdx.x;            // 1024 workgroups
    int xcd  = i & 7;
    int slot = i >> 3;                // 0..127
    int b    = xcd * 8 + (slot >> 4);
    int tt   = slot & 15;
    int t0   = tt * QBLK;

    int tid  = threadIdx.x;
    int wid  = tid >> 6;              // wave: rows [t0+32*wid, +32)
    int lane = tid & 63;
    int h    = lane >> 5;             // k-half
    int tcol = lane & 31;             // lane's own t (and m-index for reads)

    const char*  ktb = ws + (size_t)b * NKV * TILE_B;
    const char*  vtb = ws + VBASE + (size_t)b * NKV * TILE_B;
    const float* qb  = qkv + (size_t)b * 3 * CD * TD;

    __shared__ short Klds[KVB][CD];   // 16KB linear; content chunk-swizzled
    __shared__ short Vlds[CD][KVB];   // 16KB linear; content chunk-swizzled
    char* kldsb = (char*)&Klds[0][0];
    char* vldsb = (char*)&Vlds[0][0];

    int wb = wid * 1024;              // per-wave 64 lanes x 16B
    int lo = lane * 16;

    // ---- Q fragments fp32->bf16, scale*log2e folded. B[n=t][k=c] ----
    const float SCALE2 = 0.12751743f;   // log2(e)/sqrt(128)
    int tq = t0 + 32 * wid + tcol;
    bf16x8 qf[8];
    #pragma unroll
    for (int kt = 0; kt < 8; ++kt)
        #pragma unroll
        for (int j = 0; j < 8; ++j)
            qf[kt][j] = f2bf(qb[(size_t)(16 * kt + 8 * h + j) * TD + tq] * SCALE2);
    __builtin_amdgcn_sched_barrier(0);

    // ---- prologue: stage K[0] then V[0] (order matters for counted vmcnt) ----
    #pragma unroll
    for (int it = 0; it < 4; ++it)
        gl_lds16(ktb + it * 4096 + wb + lo, kldsb + it * 4096 + wb);
    #pragma unroll
    for (int it = 0; it < 4; ++it)
        gl_lds16(vtb + it * 4096 + wb + lo, vldsb + it * 4096 + wb);

    f32x16 o[4];
    #pragma unroll
    for (int mt = 0; mt < 4; ++mt) o[mt] = (f32x16)(0.0f);
    float m = -1e30f, lsum = 0.0f;    // per-lane (column tq) state

    for (int sb = 0; sb < NKV; ++sb) {
        int nxt = (sb + 1 < NKV) ? (sb + 1) : sb;   // clamped: uniform pipeline

        // ---- K[sb] resident (V[sb] still in flight) ----
        asm volatile("s_waitcnt vmcnt(4)" ::: "memory");
        __builtin_amdgcn_sched_barrier(0);
        __builtin_amdgcn_s_barrier();

        // ---- QK^T swapped: D[m=s][n=t] = sum_c K[s][c] Q[c][t] ----
        f32x16 acc[2];
        #pragma unroll
        for (int mt = 0; mt < 2; ++mt) acc[mt] = (f32x16)(0.0f);
        __builtin_amdgcn_s_setprio(1);
        #pragma unroll
        for (int kt = 0; kt < 8; ++kt) {
            #pragma unroll
            for (int mt = 0; mt < 2; ++mt) {
                bf16x8 kf = *(const bf16x8*)(kldsb + (32 * mt + tcol) * 256
                                             + (((2 * kt + h) ^ (tcol & 7)) * 16));
                acc[mt] = __builtin_amdgcn_mfma_f32_32x32x16_bf16(kf, qf[kt], acc[mt], 0, 0, 0);
            }
        }
        __builtin_amdgcn_s_setprio(0);

        // ---- Klds free -> prefetch K[nxt] (flies under softmax+PV) ----
        asm volatile("s_waitcnt lgkmcnt(0)" ::: "memory");
        __builtin_amdgcn_sched_barrier(0);
        __builtin_amdgcn_s_barrier();
        {
            const char* kn = ktb + (size_t)nxt * TILE_B;
            #pragma unroll
            for (int it = 0; it < 4; ++it)
                gl_lds16(kn + it * 4096 + wb + lo, kldsb + it * 4096 + wb);
        }

        // ---- softmax (exp2 domain), per-lane scalar state ----
        float pm = -1e30f;
        #pragma unroll
        for (int mt = 0; mt < 2; ++mt)
            #pragma unroll
            for (int r = 0; r < 16; ++r)
                pm = fmaxf(pm, acc[mt][r]);

        // defer-max: partial check equivalent to full under __all (lane^32 pair)
        if (!__all(pm <= m + 8.0f)) {
            float rm = fmaxf(pm, __shfl_xor(pm, 32, 64));
            rm = fmaxf(m, rm);
            float cr = exp2f(m - rm);
            m = rm;
            lsum *= cr;
            #pragma unroll
            for (int mt = 0; mt < 4; ++mt)
                #pragma unroll
                for (int r = 0; r < 16; ++r)
                    o[mt][r] *= cr;
        }
        #pragma unroll
        for (int mt = 0; mt < 2; ++mt)
            #pragma unroll
            for (int r = 0; r < 16; ++r) {
                acc[mt][r] = exp2f(acc[mt][r] - m);   // bounded by 2^8 when deferred
                lsum += acc[mt][r];
            }

        // ---- P^T -> PV B-frags in-register: cvt_pk + lane^32 exchange ----
        // lane holds s = 32mt + (r&3)+8(r>>2)+4h (t = tcol). Need k=s = 16kt2+8h+j.
        unsigned pb[4][4];
        #pragma unroll
        for (int mt = 0; mt < 2; ++mt) {
            #pragma unroll
            for (int e = 0; e < 2; ++e) {
                unsigned pk0, pk1, pk2, pk3;
                asm("v_cvt_pk_bf16_f32 %0, %1, %2" : "=v"(pk0)
                    : "v"(acc[mt][8 * e + 0]), "v"(acc[mt][8 * e + 1]));
                asm("v_cvt_pk_bf16_f32 %0, %1, %2" : "=v"(pk1)
                    : "v"(acc[mt][8 * e + 2]), "v"(acc[mt][8 * e + 3]));
                asm("v_cvt_pk_bf16_f32 %0, %1, %2" : "=v"(pk2)
                    : "v"(acc[mt][8 * e + 4]), "v"(acc[mt][8 * e + 5]));
                asm("v_cvt_pk_bf16_f32 %0, %1, %2" : "=v"(pk3)
                    : "v"(acc[mt][8 * e + 6]), "v"(acc[mt][8 * e + 7]));
                unsigned s0 = h ? pk0 : pk2;          // send what the peer needs
                unsigned s1 = h ? pk1 : pk3;
                unsigned r0 = (unsigned)__shfl_xor((int)s0, 32, 64);
                unsigned r1 = (unsigned)__shfl_xor((int)s1, 32, 64);
                int kt2 = 2 * mt + e;
                pb[kt2][0] = h ? r0 : pk0;
                pb[kt2][1] = h ? r1 : pk1;
                pb[kt2][2] = h ? pk2 : r0;
                pb[kt2][3] = h ? pk3 : r1;
            }
        }

        // ---- V[sb] resident (K[nxt] still in flight) ----
        asm volatile("s_waitcnt vmcnt(4)" ::: "memory");
        __builtin_amdgcn_sched_barrier(0);
        __builtin_amdgcn_s_barrier();

        // ---- PV swapped: D[m=c][n=t] = sum_s V[c][s] P^T[s][t] ----
        __builtin_amdgcn_s_setprio(1);
        #pragma unroll
        for (int kt2 = 0; kt2 < 4; ++kt2) {
            union { unsigned u[4]; bf16x8 v; } pw;
            pw.u[0] = pb[kt2][0]; pw.u[1] = pb[kt2][1];
            pw.u[2] = pb[kt2][2]; pw.u[3] = pb[kt2][3];
            #pragma unroll
            for (int mt = 0; mt < 4; ++mt) {
                bf16x8 vf = *(const bf16x8*)(vldsb + (32 * mt + tcol) * 128
                                             + (((2 * kt2 + h) ^ (tcol & 7)) * 16));
                o[mt] = __builtin_amdgcn_mfma_f32_32x32x16_bf16(vf, pw.v, o[mt], 0, 0, 0);
            }
        }
        __builtin_amdgcn_s_setprio(0);

        // ---- Vlds free -> prefetch V[nxt] (flies under next QK^T+softmax) ----
        asm volatile("s_waitcnt lgkmcnt(0)" ::: "memory");
        __builtin_amdgcn_sched_barrier(0);
        __builtin_amdgcn_s_barrier();
        {
            const char* vn = vtb + (size_t)nxt * TILE_B;
            #pragma unroll
            for (int it = 0; it < 4; ++it)
                gl_lds16(vn + it * 4096 + wb + lo, vldsb + it * 4096 + wb);
        }
    }

    // drain redundant tail prefetch before exit
    asm volatile("s_waitcnt vmcnt(0)" ::: "memory");
    __builtin_amdgcn_sched_barrier(0);

    // ---- epilogue: finish denominator across lane^32 pair, store out[c][t] ----
    lsum += __shfl_xor(lsum, 32, 64);
    float inv = 1.0f / lsum;
    float* ob = out + (size_t)b * CD * TD;
    #pragma unroll
    for (int mt = 0; mt < 4; ++mt)
        #pragma unroll
        for (int r = 0; r < 16; ++r) {
            int c = 32 * mt + (r & 3) + 8 * (r >> 2) + 4 * h;
            ob[(size_t)c * TD + tq] = o[mt][r] * inv;
        }
}

extern "C" void kernel_launch(void* const* d_in, const int* in_sizes, int n_in,
                              void* d_out, int out_size, void* d_ws, size_t ws_size,
                              hipStream_t stream)
{
    const float* qkv = (const float*)d_in[0];
    float* out = (float*)d_out;
    char* ws = (char*)d_ws;
    prepass<<<dim3(NB * 64), 256, 0, stream>>>(qkv, ws);                   // 4096 wgs
    attn_fwd<<<dim3(NB * NQT), 256, 0, stream>>>(qkv, ws, out);            // 1024 wgs
}

// Round 5
// 225.512 us; speedup vs baseline: 2.6741x; 1.0520x over previous
//
#include <hip/hip_runtime.h>
#include <math.h>

typedef __attribute__((ext_vector_type(4)))  float f32x4;
typedef __attribute__((ext_vector_type(16))) float f32x16;
typedef __attribute__((ext_vector_type(8)))  short bf16x8;

#define NB   64
#define CD   128
#define TD   2048
#define QBLK 128             // per block (4 waves x 32 rows)
#define KVB  64
#define NKV  (TD / KVB)      // 32
#define NQT  (TD / QBLK)     // 16

#define TILE_B   16384       // K tile: 64x128 bf16 ; V tile: 128x64 bf16
#define VBASE    ((size_t)NB * NKV * TILE_B)   // 33,554,432 (total ws = 64 MB)

__device__ __forceinline__ short f2bf(float f) {
    union { float f; unsigned u; } x; x.f = f;
    unsigned r = x.u + 0x7FFFu + ((x.u >> 16) & 1u);   // RNE
    return (short)(r >> 16);
}

__device__ __forceinline__ void gl_lds16(const void* g, void* l) {
    __builtin_amdgcn_global_load_lds(
        (__attribute__((address_space(1))) void*)g,
        (__attribute__((address_space(3))) void*)l, 16, 0, 0);
}

// ---------------------------------------------------------------------------
// Prepass: K -> [s][c] transposed bf16 tiles; V -> [c][s] natural bf16 tiles.
// 16B-chunk XOR swizzle pre-applied in global: stored chunk p of row r holds
// data chunk p ^ (r & 7).  (Q is consumed fp32 directly by attn.)
// ---------------------------------------------------------------------------
__global__ __launch_bounds__(256)
void prepass(const float* __restrict__ qkv, char* __restrict__ ws)
{
    int blk  = blockIdx.x;            // 64 b * 64 tiles
    int b    = blk >> 6;
    int rem  = blk & 63;
    int kind = rem >> 5;              // 0=K, 1=V
    int sb   = rem & 31;
    int s0   = sb * KVB;
    int tid  = threadIdx.x;
    const float* src = qkv + ((size_t)b * 3 + 1 + kind) * CD * TD;

    if (kind == 0) {
        // K transpose: tile[row=s'][col=c], rows of 256B = 16 chunks
        __shared__ short Tl[KVB][CD + 8];
        int su = (tid & 15) * 4;
        int cb = 4 * (tid >> 4);
        #pragma unroll
        for (int it = 0; it < 2; ++it) {
            int c0 = cb + 64 * it;
            f32x4 r0 = *(const f32x4*)&src[(size_t)(c0 + 0) * TD + s0 + su];
            f32x4 r1 = *(const f32x4*)&src[(size_t)(c0 + 1) * TD + s0 + su];
            f32x4 r2 = *(const f32x4*)&src[(size_t)(c0 + 2) * TD + s0 + su];
            f32x4 r3 = *(const f32x4*)&src[(size_t)(c0 + 3) * TD + s0 + su];
            #pragma unroll
            for (int s = 0; s < 4; ++s) {
                short4 w;
                w.x = f2bf(r0[s]); w.y = f2bf(r1[s]);
                w.z = f2bf(r2[s]); w.w = f2bf(r3[s]);
                *(short4*)&Tl[su + s][c0] = w;
            }
        }
        __syncthreads();
        char* dst = ws + ((size_t)b * NKV + sb) * TILE_B;
        #pragma unroll
        for (int it = 0; it < 4; ++it) {
            int row = (tid >> 4) + 16 * it;
            int p   = tid & 15;
            int q   = p ^ (row & 7);
            *(f32x4*)(dst + row * 256 + p * 16) = *(const f32x4*)&Tl[row][q * 8];
        }
    } else {
        // V natural: tile[row=c][col=s'], rows of 128B = 8 chunks
        char* dst = ws + VBASE + ((size_t)b * NKV + sb) * TILE_B;
        int c = tid >> 1;
        int hh = tid & 1;
        #pragma unroll
        for (int i = 0; i < 4; ++i) {
            int p = 4 * hh + i;
            int q = p ^ (c & 7);
            f32x4 a0 = *(const f32x4*)&src[(size_t)c * TD + s0 + q * 8];
            f32x4 a1 = *(const f32x4*)&src[(size_t)c * TD + s0 + q * 8 + 4];
            bf16x8 w;
            w[0] = f2bf(a0[0]); w[1] = f2bf(a0[1]); w[2] = f2bf(a0[2]); w[3] = f2bf(a0[3]);
            w[4] = f2bf(a1[0]); w[5] = f2bf(a1[1]); w[6] = f2bf(a1[2]); w[7] = f2bf(a1[3]);
            *(bf16x8*)(dst + c * 128 + p * 16) = w;
        }
    }
}

// ---------------------------------------------------------------------------
// Attention: double-buffered K/V LDS, ONE barrier per KV tile, 32-row waves
// (32x32x16 MFMA), swapped QK^T/PV, in-register P, per-lane softmax state.
// ---------------------------------------------------------------------------
__global__ __launch_bounds__(256, 2)
void attn_fwd(const float* __restrict__ qkv, const char* __restrict__ ws,
              float* __restrict__ out)
{
    // XCD-bijective decode: batch b owned by XCD b/8 (K/V stay L2-resident)
    int i    = blockIdx.x;            // 1024 workgroups
    int xcd  = i & 7;
    int slot = i >> 3;                // 0..127
    int b    = xcd * 8 + (slot >> 4);
    int tt   = slot & 15;
    int t0   = tt * QBLK;

    int tid  = threadIdx.x;
    int wid  = tid >> 6;              // wave: rows [t0+32*wid, +32)
    int lane = tid & 63;
    int h    = lane >> 5;             // k-half
    int tcol = lane & 31;             // lane's own t (and m-index for reads)

    const char*  ktb = ws + (size_t)b * NKV * TILE_B;
    const char*  vtb = ws + VBASE + (size_t)b * NKV * TILE_B;
    const float* qb  = qkv + (size_t)b * 3 * CD * TD;

    __shared__ short Klds[2][KVB][CD];   // 2 x 16KB, linear; content chunk-swizzled
    __shared__ short Vlds[2][CD][KVB];   // 2 x 16KB
    char* k0 = (char*)&Klds[0][0][0];
    char* k1 = (char*)&Klds[1][0][0];
    char* v0 = (char*)&Vlds[0][0][0];
    char* v1 = (char*)&Vlds[1][0][0];

    int wb = wid * 1024;              // per-wave 64 lanes x 16B
    int lo = lane * 16;

    // ---- Q fragments fp32->bf16, scale*log2e folded. B[n=t][k=c] ----
    const float SCALE2 = 0.12751743f;   // log2(e)/sqrt(128)
    int tq = t0 + 32 * wid + tcol;
    bf16x8 qf[8];
    #pragma unroll
    for (int kt = 0; kt < 8; ++kt)
        #pragma unroll
        for (int j = 0; j < 8; ++j)
            qf[kt][j] = f2bf(qb[(size_t)(16 * kt + 8 * h + j) * TD + tq] * SCALE2);
    __builtin_amdgcn_sched_barrier(0);

    // ---- prologue: stage tile 0 into buffer 0 (K then V) ----
    #pragma unroll
    for (int it = 0; it < 4; ++it)
        gl_lds16(ktb + it * 4096 + wb + lo, k0 + it * 4096 + wb);
    #pragma unroll
    for (int it = 0; it < 4; ++it)
        gl_lds16(vtb + it * 4096 + wb + lo, v0 + it * 4096 + wb);

    f32x16 o[4];
    #pragma unroll
    for (int mt = 0; mt < 4; ++mt) o[mt] = (f32x16)(0.0f);
    float m = -1e30f, lsum = 0.0f;    // per-lane (column tq) state

    auto ITER = [&](int sb, char* kc, char* vc, char* kn, char* vn)
        __attribute__((always_inline))
    {
        int nxt = (sb + 1 < NKV) ? (sb + 1) : sb;   // clamped: uniform pipeline

        // ---- tile sb resident; all waves done reading the other buffer ----
        asm volatile("s_waitcnt vmcnt(0)" ::: "memory");
        __builtin_amdgcn_sched_barrier(0);
        __builtin_amdgcn_s_barrier();
        __builtin_amdgcn_sched_barrier(0);

        // ---- prefetch tile sb+1 into the other buffer (flies under compute) ----
        {
            const char* kg = ktb + (size_t)nxt * TILE_B;
            const char* vg = vtb + (size_t)nxt * TILE_B;
            #pragma unroll
            for (int it = 0; it < 4; ++it)
                gl_lds16(kg + it * 4096 + wb + lo, kn + it * 4096 + wb);
            #pragma unroll
            for (int it = 0; it < 4; ++it)
                gl_lds16(vg + it * 4096 + wb + lo, vn + it * 4096 + wb);
        }

        // ---- QK^T swapped: D[m=s][n=t] = sum_c K[s][c] Q[c][t] ----
        f32x16 acc[2];
        #pragma unroll
        for (int mt = 0; mt < 2; ++mt) acc[mt] = (f32x16)(0.0f);
        __builtin_amdgcn_s_setprio(1);
        #pragma unroll
        for (int kt = 0; kt < 8; ++kt) {
            #pragma unroll
            for (int mt = 0; mt < 2; ++mt) {
                bf16x8 kf = *(const bf16x8*)(kc + (32 * mt + tcol) * 256
                                             + (((2 * kt + h) ^ (tcol & 7)) * 16));
                acc[mt] = __builtin_amdgcn_mfma_f32_32x32x16_bf16(kf, qf[kt], acc[mt], 0, 0, 0);
            }
        }
        __builtin_amdgcn_s_setprio(0);

        // ---- softmax (exp2 domain), per-lane scalar state, parallel chains ----
        float px0 = -1e30f, px1 = -1e30f, px2 = -1e30f, px3 = -1e30f;
        #pragma unroll
        for (int mt = 0; mt < 2; ++mt)
            #pragma unroll
            for (int r = 0; r < 16; r += 4) {
                px0 = fmaxf(px0, acc[mt][r + 0]);
                px1 = fmaxf(px1, acc[mt][r + 1]);
                px2 = fmaxf(px2, acc[mt][r + 2]);
                px3 = fmaxf(px3, acc[mt][r + 3]);
            }
        float pm = fmaxf(fmaxf(px0, px1), fmaxf(px2, px3));

        // defer-max: partial check equivalent to full under __all (lane^32 pair)
        if (!__all(pm <= m + 8.0f)) {
            float rm = fmaxf(pm, __shfl_xor(pm, 32, 64));
            rm = fmaxf(m, rm);
            float cr = exp2f(m - rm);
            m = rm;
            lsum *= cr;
            #pragma unroll
            for (int mt = 0; mt < 4; ++mt)
                #pragma unroll
                for (int r = 0; r < 16; ++r)
                    o[mt][r] *= cr;
        }
        float s0a = 0.f, s1a = 0.f, s2a = 0.f, s3a = 0.f;
        #pragma unroll
        for (int mt = 0; mt < 2; ++mt)
            #pragma unroll
            for (int r = 0; r < 16; r += 4) {
                acc[mt][r + 0] = exp2f(acc[mt][r + 0] - m);
                acc[mt][r + 1] = exp2f(acc[mt][r + 1] - m);
                acc[mt][r + 2] = exp2f(acc[mt][r + 2] - m);
                acc[mt][r + 3] = exp2f(acc[mt][r + 3] - m);
                s0a += acc[mt][r + 0];
                s1a += acc[mt][r + 1];
                s2a += acc[mt][r + 2];
                s3a += acc[mt][r + 3];
            }
        lsum += (s0a + s1a) + (s2a + s3a);

        // ---- P^T -> PV B-frags in-register: cvt_pk + lane^32 exchange ----
        unsigned pb[4][4];
        #pragma unroll
        for (int mt = 0; mt < 2; ++mt) {
            #pragma unroll
            for (int e = 0; e < 2; ++e) {
                unsigned pk0, pk1, pk2, pk3;
                asm("v_cvt_pk_bf16_f32 %0, %1, %2" : "=v"(pk0)
                    : "v"(acc[mt][8 * e + 0]), "v"(acc[mt][8 * e + 1]));
                asm("v_cvt_pk_bf16_f32 %0, %1, %2" : "=v"(pk1)
                    : "v"(acc[mt][8 * e + 2]), "v"(acc[mt][8 * e + 3]));
                asm("v_cvt_pk_bf16_f32 %0, %1, %2" : "=v"(pk2)
                    : "v"(acc[mt][8 * e + 4]), "v"(acc[mt][8 * e + 5]));
                asm("v_cvt_pk_bf16_f32 %0, %1, %2" : "=v"(pk3)
                    : "v"(acc[mt][8 * e + 6]), "v"(acc[mt][8 * e + 7]));
                unsigned sA = h ? pk0 : pk2;          // send what the peer needs
                unsigned sB = h ? pk1 : pk3;
                unsigned r0 = (unsigned)__shfl_xor((int)sA, 32, 64);
                unsigned r1 = (unsigned)__shfl_xor((int)sB, 32, 64);
                int kt2 = 2 * mt + e;
                pb[kt2][0] = h ? r0 : pk0;
                pb[kt2][1] = h ? r1 : pk1;
                pb[kt2][2] = h ? pk2 : r0;
                pb[kt2][3] = h ? pk3 : r1;
            }
        }

        // ---- PV swapped: D[m=c][n=t] = sum_s V[c][s] P^T[s][t] ----
        __builtin_amdgcn_s_setprio(1);
        #pragma unroll
        for (int kt2 = 0; kt2 < 4; ++kt2) {
            union { unsigned u[4]; bf16x8 v; } pw;
            pw.u[0] = pb[kt2][0]; pw.u[1] = pb[kt2][1];
            pw.u[2] = pb[kt2][2]; pw.u[3] = pb[kt2][3];
            #pragma unroll
            for (int mt = 0; mt < 4; ++mt) {
                bf16x8 vf = *(const bf16x8*)(vc + (32 * mt + tcol) * 128
                                             + (((2 * kt2 + h) ^ (tcol & 7)) * 16));
                o[mt] = __builtin_amdgcn_mfma_f32_32x32x16_bf16(vf, pw.v, o[mt], 0, 0, 0);
            }
        }
        __builtin_amdgcn_s_setprio(0);
    };

    #pragma unroll 1
    for (int s2 = 0; s2 < NKV; s2 += 2) {
        ITER(s2,     k0, v0, k1, v1);
        ITER(s2 + 1, k1, v1, k0, v0);
    }

    // drain redundant tail prefetch before exit
    asm volatile("s_waitcnt vmcnt(0)" ::: "memory");
    __builtin_amdgcn_sched_barrier(0);

    // ---- epilogue: finish denominator across lane^32 pair, store out[c][t] ----
    lsum += __shfl_xor(lsum, 32, 64);
    float inv = 1.0f / lsum;
    float* ob = out + (size_t)b * CD * TD;
    #pragma unroll
    for (int mt = 0; mt < 4; ++mt)
        #pragma unroll
        for (int r = 0; r < 16; ++r) {
            int c = 32 * mt + (r & 3) + 8 * (r >> 2) + 4 * h;
            ob[(size_t)c * TD + tq] = o[mt][r] * inv;
        }
}

extern "C" void kernel_launch(void* const* d_in, const int* in_sizes, int n_in,
                              void* d_out, int out_size, void* d_ws, size_t ws_size,
                              hipStream_t stream)
{
    const float* qkv = (const float*)d_in[0];
    float* out = (float*)d_out;
    char* ws = (char*)d_ws;
    prepass<<<dim3(NB * 64), 256, 0, stream>>>(qkv, ws);                   // 4096 wgs
    attn_fwd<<<dim3(NB * NQT), 256, 0, stream>>>(qkv, ws, out);            // 1024 wgs
}